// Round 5
// baseline (655.276 us; speedup 1.0000x reference)
//
#include <hip/hip_runtime.h>
#include <math.h>

#define NB      512
#define NELEC   30
#define NATOMS  10
#define NNEN    40      // en graph nodes: 30 electrons + 10 atoms
#define FEAT    64
#define KRBF    64
#define BLOCK   1024
#define NWAVES  (BLOCK/64)
#define NPEE    435     // unique elec-elec pairs
#define NPEN    300     // unique elec-nuc pairs
#define TILE    32      // feature tile held per thread (facc) / in fT
#define FPAD    33      // fT row stride (+1): write banks (p+ff)%32 -> 2-way = free

// ---------------- LDS layout (floats) ----------------
// xyz[96] | axyz[32] | kee(double)@128 | hS[40][64] | aggS[40][64] | fT[435][33]
// ee phase: h lives in hS, agg in aggS.  en phase: h lives in aggS, agg in hS
// (avoids an extra copy segment; each buffer's writers/readers are barrier-split).
#define OFF_XYZ   0
#define OFF_AXYZ  96
#define OFF_KEE   128
#define HS_OFF    132
#define AGG_OFF   (HS_OFF + NNEN*FEAT)      // 2692
#define FT_OFF    (AGG_OFF + NNEN*FEAT)     // 5252
#define SM_TOTAL  (FT_OFF + NPEE*FPAD)      // 19607 fl = 78428 B -> 2 blocks/CU

// triangular pair index base for row i (i<j pairs of 30 electrons)
__device__ __forceinline__ int ee_base(int i) { return 29*i - ((i*(i-1))>>1); }

// RBF filter: facc = tanh(bf + sum_k exp(-(dd-ck)^2) * wf[k]) for one
// 32-feature half. uoff is an SGPR (readfirstlane) so weight rows stay
// scalar loads. FP sequence identical to R3/R4.
__device__ __forceinline__ void rbf_filter(float dd, const float* __restrict__ wf,
                                           const float* __restrict__ bf,
                                           int uoff, float* __restrict__ facc)
{
    const float* bfH = bf + uoff;
    #pragma unroll
    for (int f = 0; f < TILE; ++f) facc[f] = bfH[f];
    #pragma unroll 2
    for (int k = 0; k < KRBF; ++k) {
        const float ck = (float)((double)k * (8.0/63.0));
        const float t  = dd - ck;
        const float rk = expf(-t*t);
        const float* wrow = wf + k*FEAT + uoff;
        #pragma unroll
        for (int f = 0; f < TILE; ++f) facc[f] = fmaf(rk, wrow[f], facc[f]);
    }
    #pragma unroll
    for (int f = 0; f < TILE; ++f) facc[f] = tanhf(facc[f]);
}

__device__ __forceinline__ void ft_write(const float* __restrict__ facc,
                                         float* __restrict__ fT, int p)
{
    #pragma unroll
    for (int ff = 0; ff < TILE; ++ff) fT[p*FPAD + ff] = facc[ff];
}

// dense update: hbuf[i] += tanh(aggbuf[i] @ wl + bl), wave per node.
__device__ __forceinline__ void dense_update(const float* __restrict__ aggbuf,
                                             float* __restrict__ hbuf,
                                             const float* __restrict__ wlL,
                                             const float* __restrict__ blL,
                                             int N, int w, int lane)
{
    for (int i = w; i < N; i += NWAVES) {
        float a2 = 0.f;
        const float4* arow = reinterpret_cast<const float4*>(aggbuf + i*FEAT);
        #pragma unroll
        for (int k = 0; k < FEAT/4; ++k) {
            float4 av = arow[k];                      // uniform -> LDS broadcast
            a2 = fmaf(av.x, wlL[(4*k+0)*FEAT + lane], a2);
            a2 = fmaf(av.y, wlL[(4*k+1)*FEAT + lane], a2);
            a2 = fmaf(av.z, wlL[(4*k+2)*FEAT + lane], a2);
            a2 = fmaf(av.w, wlL[(4*k+3)*FEAT + lane], a2);
        }
        hbuf[i*FEAT + lane] += tanhf(a2 + blL[lane]);
    }
}

// ==========================================================================
// Fused ee+en GNN, tile-through-LDS filt, 2 blocks/CU.
// Thread (pair p, half t) keeps facc[32] in registers for the whole phase;
// fT[435][33] holds one 32-feature tile of filt at a time (rewritten per
// (layer, tile) — a 32-store copy, trivial vs the 113 KB full buffer that
// capped occupancy at 1 block/CU in R3/R4).
// ==========================================================================
__global__ __launch_bounds__(BLOCK)
void fused_kernel(const float* __restrict__ pos,
                  const float* __restrict__ atoms,
                  const float* __restrict__ emb_ee,
                  const float* __restrict__ wf_ee,
                  const float* __restrict__ bf_ee,
                  const float* __restrict__ wl_ee,
                  const float* __restrict__ bl_ee,
                  const float* __restrict__ wr_ee,
                  const float* __restrict__ br_ee,
                  const float* __restrict__ emb_en,
                  const float* __restrict__ wf_en,
                  const float* __restrict__ bf_en,
                  const float* __restrict__ wl_en,
                  const float* __restrict__ bl_en,
                  const float* __restrict__ wr_en,
                  const float* __restrict__ br_en,
                  const int*   __restrict__ ee_ty,
                  const int*   __restrict__ en_ty,
                  float*       __restrict__ out)
{
    extern __shared__ float sm[];
    float*  xyz  = sm + OFF_XYZ;     // [96]
    float*  axyz = sm + OFF_AXYZ;    // [32]
    double* keeP = reinterpret_cast<double*>(sm + OFF_KEE);
    float*  hS   = sm + HS_OFF;      // [40][64]  ee-h   / en-agg
    float*  aggS = sm + AGG_OFF;     // [40][64]  ee-agg / en-h
    float*  fT   = sm + FT_OFF;      // [435][33] one filt tile

    const int tid  = threadIdx.x;
    const int b    = blockIdx.x;
    const int lane = tid & 63;
    const int w    = tid >> 6;

    // ---- wave roles ----
    // ee filter: waves 0-13 (half0 = 0-6 t=0, half1 = 7-13 t=1) -> SIMD (4,4,3,3)
    const int  ee_t   = (w >= 7) ? 1 : 0;
    const int  ee_p   = ((w >= 7 ? w - 7 : w) << 6) | lane;
    const bool ee_ok  = (w < 14) && (ee_p < NPEE);
    // en filter: active waves {0,1,2,3,4, 9,10,11,13,14} -> SIMD (2,3,3,2)
    const int  v      = w & 7;
    const int  en_blk = (w < 8) ? (v < 5 ? v : -1)
                                : ((v >= 1 && v <= 3) ? v - 1
                                   : (v == 5 || v == 6) ? v - 2 : -1);
    const int  en_t   = (w >= 8) ? 1 : 0;
    const int  en_p   = (en_blk < 0) ? 0 : ((en_blk << 6) | lane);
    const bool en_ok  = (en_blk >= 0) && (en_p < NPEN);
    // en h-init: waves {5,6,7,8,12} (disjoint from en-filter and readout w15)
    const int  hr     = (w == 5) ? 0 : (w == 6) ? 1 : (w == 7) ? 2
                      : (w == 8) ? 3 : (w == 12) ? 4 : -1;

    const int uoff_ee = __builtin_amdgcn_readfirstlane(ee_t * TILE);
    const int uoff_en = __builtin_amdgcn_readfirstlane(en_t * TILE);

    float facc[TILE];

    // ---------------- S0: stage positions + atoms + ee h-init ----------------
    for (int idx = tid; idx < NELEC*3; idx += BLOCK) xyz[idx] = pos[b*NELEC*3 + idx];
    for (int idx = tid; idx < NATOMS*3; idx += BLOCK) axyz[idx] = atoms[idx];
    for (int idx = tid; idx < NELEC*FEAT; idx += BLOCK) {
        int n = idx >> 6, f = idx & 63;
        hS[idx] = emb_ee[ee_ty[n]*FEAT + f];
    }
    __syncthreads();

    // ---------------- S1: ee filter compute + tile0 write ----------------
    if (ee_ok) {
        int i = 0, rem = ee_p;
        while (rem >= NELEC - 1 - i) { rem -= NELEC - 1 - i; ++i; }
        const int j = i + 1 + rem;
        const float dx = xyz[3*i+0] - xyz[3*j+0];
        const float dy = xyz[3*i+1] - xyz[3*j+1];
        const float dz = xyz[3*i+2] - xyz[3*j+2];
        const float dd = sqrtf(dx*dx + dy*dy + dz*dz);
        rbf_filter(dd, wf_ee, bf_ee, uoff_ee, facc);
        if (ee_t == 0) ft_write(facc, fT, ee_p);
    }
    __syncthreads();

    // ---------------- ee interaction layers ----------------
    #pragma unroll
    for (int l = 0; l < 2; ++l) {
        const float* wlL = wl_ee + l*FEAT*FEAT;
        const float* blL = bl_ee + l*FEAT;

        #pragma unroll
        for (int t = 0; t < 2; ++t) {
            if (t == 1) {                      // tile1 into fT
                if (ee_ok && ee_t == 1) ft_write(facc, fT, ee_p);
                __syncthreads();
            }
            // agg tile: thread (i, ff), f = t*32+ff; j-ascending chain
            if (tid < NELEC*TILE) {
                const int i  = tid >> 5;
                const int ff = tid & 31;
                const int f  = t*TILE + ff;
                float a = 0.f;
                #pragma unroll
                for (int j = 0; j < NELEC; ++j) {
                    if (j != i) {
                        int pp = (j < i) ? (ee_base(j) + (i - j - 1))
                                         : (ee_base(i) + (j - i - 1));
                        a = fmaf(hS[j*FEAT + f], fT[pp*FPAD + ff], a);
                    }
                }
                aggS[i*FEAT + f] = a;
            }
            __syncthreads();
        }
        // dense (reads aggS, rw hS) + prefill tile0 for next layer (disjoint)
        dense_update(aggS, hS, wlL, blL, NELEC, w, lane);
        if (l == 0 && ee_ok && ee_t == 0) ft_write(facc, fT, ee_p);
        __syncthreads();
    }

    // ---------------- S10: ee readout || en filter+tile0 || en h-init ------
    if (w == 15) {   // kee = (sum_n hS[n]) . wr + br  (f64 tail)
        float s = 0.f;
        #pragma unroll
        for (int n = 0; n < NELEC; ++n) s += hS[n*FEAT + lane];
        double dv = (double)s * (double)wr_ee[lane];
        #pragma unroll
        for (int o = 32; o > 0; o >>= 1) dv += __shfl_xor(dv, o, 64);
        if (lane == 0) *keeP = dv + (double)br_ee[0];
    }
    if (hr >= 0) {   // en h -> aggS (free: last read was ee dense, barrier'd)
        #pragma unroll
        for (int r = 0; r < 8; ++r) {
            const int idx = hr*64 + lane + r*320;
            aggS[idx] = emb_en[en_ty[idx >> 6]*FEAT + (idx & 63)];
        }
    }
    if (en_ok) {
        const int a = en_p / NELEC;
        const int e = en_p - a*NELEC;
        const float dx = xyz[3*e+0] - axyz[3*a+0];
        const float dy = xyz[3*e+1] - axyz[3*a+1];
        const float dz = xyz[3*e+2] - axyz[3*a+2];
        const float dd = sqrtf(dx*dx + dy*dy + dz*dz);
        rbf_filter(dd, wf_en, bf_en, uoff_en, facc);
        if (en_t == 0) ft_write(facc, fT, en_p);
    }
    __syncthreads();

    // ---------------- en interaction layers (h = aggS, agg = hS) ----------
    #pragma unroll
    for (int l = 0; l < 2; ++l) {
        const float* wlL = wl_en + l*FEAT*FEAT;
        const float* blL = bl_en + l*FEAT;

        #pragma unroll
        for (int t = 0; t < 2; ++t) {
            if (t == 1) {
                if (en_ok && en_t == 1) ft_write(facc, fT, en_p);
                __syncthreads();
            }
            // bipartite agg tile: 40 nodes x 32 ff = 1280 items, 2 passes
            #pragma unroll
            for (int pass = 0; pass < 2; ++pass) {
                const int idx = tid + pass*BLOCK;
                if (idx < NNEN*TILE) {
                    const int n  = idx >> 5;
                    const int ff = idx & 31;
                    const int f  = t*TILE + ff;
                    float a = 0.f;
                    if (n < NELEC) {            // electron node: atoms ascending
                        #pragma unroll
                        for (int at = 0; at < NATOMS; ++at)
                            a = fmaf(aggS[(NELEC+at)*FEAT + f],
                                     fT[(at*NELEC + n)*FPAD + ff], a);
                    } else {                    // atom node: electrons ascending
                        const int at = n - NELEC;
                        #pragma unroll
                        for (int e2 = 0; e2 < NELEC; ++e2)
                            a = fmaf(aggS[e2*FEAT + f],
                                     fT[(at*NELEC + e2)*FPAD + ff], a);
                    }
                    hS[n*FEAT + f] = a;
                }
            }
            __syncthreads();
        }
        dense_update(hS, aggS, wlL, blL, NNEN, w, lane);
        if (l == 0 && en_ok && en_t == 0) ft_write(facc, fT, en_p);
        __syncthreads();
    }

    // ---------------- final readout + combine ----------------
    if (w == 0) {
        float s = 0.f;
        #pragma unroll
        for (int n = 0; n < NNEN; ++n) s += aggS[n*FEAT + lane];
        double dv = (double)s * (double)wr_en[lane];
        #pragma unroll
        for (int o = 32; o > 0; o >>= 1) dv += __shfl_xor(dv, o, 64);
        if (lane == 0) out[b] = (float)exp(dv + (double)br_en[0] + *keeP);
    }
}

// ==========================================================================
extern "C" void kernel_launch(void* const* d_in, const int* in_sizes, int n_in,
                              void* d_out, int out_size, void* d_ws, size_t ws_size,
                              hipStream_t stream) {
    const float* pos    = (const float*)d_in[0];
    const float* atoms  = (const float*)d_in[1];
    const float* emb_ee = (const float*)d_in[2];
    const float* wf_ee  = (const float*)d_in[3];
    const float* bf_ee  = (const float*)d_in[4];
    const float* wl_ee  = (const float*)d_in[5];
    const float* bl_ee  = (const float*)d_in[6];
    const float* wr_ee  = (const float*)d_in[7];
    const float* br_ee  = (const float*)d_in[8];
    const float* emb_en = (const float*)d_in[9];
    const float* wf_en  = (const float*)d_in[10];
    const float* bf_en  = (const float*)d_in[11];
    const float* wl_en  = (const float*)d_in[12];
    const float* bl_en  = (const float*)d_in[13];
    const float* wr_en  = (const float*)d_in[14];
    const float* br_en  = (const float*)d_in[15];
    const int*   ee_ty  = (const int*)d_in[18];
    const int*   en_ty  = (const int*)d_in[21];

    float* out = (float*)d_out;        // [512]

    (void)hipFuncSetAttribute((const void*)fused_kernel,
            hipFuncAttributeMaxDynamicSharedMemorySize, SM_TOTAL*(int)sizeof(float));

    fused_kernel<<<NB, BLOCK, SM_TOTAL*sizeof(float), stream>>>(
        pos, atoms,
        emb_ee, wf_ee, bf_ee, wl_ee, bl_ee, wr_ee, br_ee,
        emb_en, wf_en, bf_en, wl_en, bl_en, wr_en, br_en,
        ee_ty, en_ty, out);
}

// Round 6
// 264.938 us; speedup vs baseline: 2.4733x; 2.4733x over previous
//
#include <hip/hip_runtime.h>
#include <math.h>

#define NB      512
#define NELEC   30
#define NATOMS  10
#define NNEN    40      // en graph nodes: 30 electrons + 10 atoms
#define FEAT    64
#define KRBF    64
#define BLOCK   1024
#define NWAVES  (BLOCK/64)
#define NPEE    435     // unique elec-elec pairs
#define NPEN    300     // unique elec-nuc pairs
#define TILE    32      // feature tile per filter thread (pair-half)
#define FPAD    65      // filt row stride (+1): lanes hit banks (p+f)%32, 2-way = free

// ---------------- LDS layout (floats) ----------------
// xyz[96] | axyz[32] | kee(double)@128 | h0[40][64] | h1[40][64] |
// filt[435][65] | wrS[16][64] | wfS[64][64] | bfS[64]
#define OFF_XYZ   0
#define OFF_AXYZ  96
#define OFF_KEE   128                       // byte 512, 8B-aligned
#define H0_OFF    132
#define H1_OFF    (H0_OFF + NNEN*FEAT)      // 2692
#define FILT_OFF  (H1_OFF + NNEN*FEAT)      // 5252
#define WR_OFF    33528                     // 5252 + 435*65 = 33527, +1 align16B
#define WF_OFF    (WR_OFF + NWAVES*64)      // 34552
#define BF_OFF    (WF_OFF + KRBF*FEAT)      // 38648
#define SM_TOTAL  (BF_OFF + FEAT)           // 38712 fl = 154848 B -> 1 block/CU

// triangular pair index base for row i (i<j pairs of 30 electrons)
__device__ __forceinline__ int ee_base(int i) { return 29*i - ((i*(i-1))>>1); }

// ==========================================================================
// RBF filter, weights from LDS: facc = tanh(bf + sum_k exp(-(dd-ck)^2)*wf[k]).
// wfS/bfS are LDS-staged; uoff is a readfirstlane SGPR, so every weight read
// is a uniform-address ds_read (hardware broadcast, immediate offset, ~60cy)
// instead of R4's s_load chain that stalled on scalar-cache misses (~200cy).
// FP value sequence identical to the R3/R4 passing kernels.
// ==========================================================================
__device__ __forceinline__ void rbf_filter(float dd,
                                           const float* __restrict__ wfS,
                                           const float* __restrict__ bfS,
                                           int uoff, float* __restrict__ dstrow)
{
    float facc[TILE];
    const float* bfH = bfS + uoff;                   // uniform -> LDS broadcast
    #pragma unroll
    for (int f = 0; f < TILE; ++f) facc[f] = bfH[f];
    #pragma unroll 2
    for (int k = 0; k < KRBF; ++k) {
        const float ck = (float)((double)k * (8.0/63.0));
        const float t  = dd - ck;
        const float rk = expf(-t*t);
        const float* wrow = wfS + k*FEAT + uoff;     // uniform row, imm offsets
        #pragma unroll
        for (int f = 0; f < TILE; ++f) facc[f] = fmaf(rk, wrow[f], facc[f]);
    }
    #pragma unroll
    for (int ff = 0; ff < TILE; ++ff) dstrow[uoff + ff] = tanhf(facc[ff]);
}

// ==========================================================================
// Fused per-wave ee layer (R4 structure): wave = node, lane = feature.
// iu = readfirstlane(i) -> pair-index/row-base arithmetic goes to SALU.
// Message sum -> private LDS row roundtrip (same-wave, lgkmcnt only) ->
// float4-broadcast dense -> hn. One barrier per layer (caller).
// ==========================================================================
__device__ __forceinline__ void ee_layer(const float* __restrict__ hc,
                                         float* __restrict__ hn,
                                         const float* __restrict__ filt,
                                         float* __restrict__ wr,
                                         const float* __restrict__ wlL,
                                         const float* __restrict__ blL,
                                         int w, int lane)
{
    for (int i = w; i < NELEC; i += NWAVES) {
        const int iu = __builtin_amdgcn_readfirstlane(i);   // SALU addressing
        float a = 0.f;
        #pragma unroll
        for (int j = 0; j < NELEC; ++j) {
            if (j != iu) {   // scalar compare (j compile-time, iu SGPR)
                int pp = (j < iu) ? (ee_base(j) + (iu - j - 1))
                                  : (ee_base(iu) + (j - iu - 1));
                a = fmaf(hc[j*FEAT + lane], filt[pp*FPAD + lane], a);
            }
        }
        wr[lane] = a;                         // same-wave roundtrip
        float a2 = 0.f;
        const float4* arow = reinterpret_cast<const float4*>(wr);
        #pragma unroll
        for (int k = 0; k < FEAT/4; ++k) {
            float4 av = arow[k];              // uniform -> LDS broadcast b128
            a2 = fmaf(av.x, wlL[(4*k+0)*FEAT + lane], a2);
            a2 = fmaf(av.y, wlL[(4*k+1)*FEAT + lane], a2);
            a2 = fmaf(av.z, wlL[(4*k+2)*FEAT + lane], a2);
            a2 = fmaf(av.w, wlL[(4*k+3)*FEAT + lane], a2);
        }
        hn[iu*FEAT + lane] = hc[iu*FEAT + lane] + tanhf(a2 + blL[lane]);
    }
}

__device__ __forceinline__ void en_layer(const float* __restrict__ hc,
                                         float* __restrict__ hn,
                                         const float* __restrict__ filt,
                                         float* __restrict__ wr,
                                         const float* __restrict__ wlL,
                                         const float* __restrict__ blL,
                                         int w, int lane)
{
    for (int n = w; n < NNEN; n += NWAVES) {
        const int nu = __builtin_amdgcn_readfirstlane(n);
        float a = 0.f;
        if (nu < NELEC) {            // scalar branch: electron node, atoms asc
            #pragma unroll
            for (int at = 0; at < NATOMS; ++at)
                a = fmaf(hc[(NELEC+at)*FEAT + lane],
                         filt[(at*NELEC + nu)*FPAD + lane], a);
        } else {                     // atom node: electrons ascending
            const int at = nu - NELEC;
            #pragma unroll
            for (int e2 = 0; e2 < NELEC; ++e2)
                a = fmaf(hc[e2*FEAT + lane],
                         filt[(at*NELEC + e2)*FPAD + lane], a);
        }
        wr[lane] = a;
        float a2 = 0.f;
        const float4* arow = reinterpret_cast<const float4*>(wr);
        #pragma unroll
        for (int k = 0; k < FEAT/4; ++k) {
            float4 av = arow[k];
            a2 = fmaf(av.x, wlL[(4*k+0)*FEAT + lane], a2);
            a2 = fmaf(av.y, wlL[(4*k+1)*FEAT + lane], a2);
            a2 = fmaf(av.z, wlL[(4*k+2)*FEAT + lane], a2);
            a2 = fmaf(av.w, wlL[(4*k+3)*FEAT + lane], a2);
        }
        hn[nu*FEAT + lane] = hc[nu*FEAT + lane] + tanhf(a2 + blL[lane]);
    }
}

// ==========================================================================
// Fused ee+en GNN. One block per batch. out[b] = exp(k_ee + k_en).
// No register state crosses any barrier (R5 lesson: the allocator re-spills
// cross-barrier live ranges per segment -> 2.1 GB scratch traffic).
// Segments (8 barriers): S0 stage(xyz,atoms,wf_ee,bf_ee,h0ee) | S1 ee-filter
// | ee-l0 h0->h1 | ee-l1 h1->h0 | S5a stage(wf_en,bf_en)+ee-readout(w15,h0)
// | S5b en-filter + en-h1-init | en-l0 h1->h0 | en-l1 h0->h1 | readout(w0,h1)
// ==========================================================================
__global__ __launch_bounds__(BLOCK)
void fused_kernel(const float* __restrict__ pos,
                  const float* __restrict__ atoms,
                  const float* __restrict__ emb_ee,
                  const float* __restrict__ wf_ee,
                  const float* __restrict__ bf_ee,
                  const float* __restrict__ wl_ee,
                  const float* __restrict__ bl_ee,
                  const float* __restrict__ wr_ee,
                  const float* __restrict__ br_ee,
                  const float* __restrict__ emb_en,
                  const float* __restrict__ wf_en,
                  const float* __restrict__ bf_en,
                  const float* __restrict__ wl_en,
                  const float* __restrict__ bl_en,
                  const float* __restrict__ wr_en,
                  const float* __restrict__ br_en,
                  const int*   __restrict__ ee_ty,
                  const int*   __restrict__ en_ty,
                  float*       __restrict__ out)
{
    extern __shared__ float sm[];
    float*  xyz  = sm + OFF_XYZ;     // [96]
    float*  axyz = sm + OFF_AXYZ;    // [32]
    double* keeP = reinterpret_cast<double*>(sm + OFF_KEE);
    float*  h0   = sm + H0_OFF;      // [40][64]
    float*  h1   = sm + H1_OFF;      // [40][64]
    float*  filt = sm + FILT_OFF;    // [435][65]
    float*  wrS  = sm + WR_OFF;      // [16][64]
    float*  wfS  = sm + WF_OFF;      // [64][64] staged filter weights
    float*  bfS  = sm + BF_OFF;      // [64]

    const int tid  = threadIdx.x;
    const int b    = blockIdx.x;
    const int lane = tid & 63;
    const int w    = tid >> 6;
    const int q    = tid & 511;      // pair slot within block-half
    float* wr = wrS + w*64;          // this wave's private agg row

    // ---- wave roles ----
    // ee filter: waves 0-13 (t = w>=7), pair = (w%7)*64+lane -> SIMD (4,4,3,3)
    const int  ee_t   = (w >= 7) ? 1 : 0;
    const int  ee_p   = ((w >= 7 ? w - 7 : w) << 6) | lane;
    const bool ee_ok  = (w < 14) && (ee_p < NPEE);
    // en filter: active waves {0,1,2,3,4, 9,10,11,13,14} -> SIMD (2,3,3,2)
    const int  v      = w & 7;
    const int  en_blk = (w < 8) ? (v < 5 ? v : -1)
                                : ((v >= 1 && v <= 3) ? v - 1
                                   : (v == 5 || v == 6) ? v - 2 : -1);
    const int  en_t   = (w >= 8) ? 1 : 0;
    const int  en_p   = (en_blk < 0) ? 0 : ((en_blk << 6) | lane);
    const bool en_ok  = (en_blk >= 0) && (en_p < NPEN);
    // en h-init: waves {5,6,7,8,12} (disjoint from en-filter waves)
    const int  hr     = (w == 5) ? 0 : (w == 6) ? 1 : (w == 7) ? 2
                      : (w == 8) ? 3 : (w == 12) ? 4 : -1;

    const int uoff_ee = __builtin_amdgcn_readfirstlane(ee_t * TILE);
    const int uoff_en = __builtin_amdgcn_readfirstlane(en_t * TILE);

    // ---------------- S0: stage xyz, atoms, wf_ee, bf_ee, ee h0 ----------------
    for (int idx = tid; idx < NELEC*3; idx += BLOCK) xyz[idx] = pos[b*NELEC*3 + idx];
    for (int idx = tid; idx < NATOMS*3; idx += BLOCK) axyz[idx] = atoms[idx];
    {   // wf_ee: 4096 floats = 1024 float4, one per thread
        const float4* src = reinterpret_cast<const float4*>(wf_ee);
        float4* dst = reinterpret_cast<float4*>(wfS);
        dst[tid] = src[tid];
        if (tid < FEAT) bfS[tid] = bf_ee[tid];
    }
    for (int idx = tid; idx < NELEC*FEAT; idx += BLOCK) {
        int n = idx >> 6, f = idx & 63;
        h0[idx] = emb_ee[ee_ty[n]*FEAT + f];
    }
    __syncthreads();

    // ---------------- S1: ee filter (waves 0-13) ----------------
    if (ee_ok) {
        int i = 0, rem = ee_p;
        while (rem >= NELEC - 1 - i) { rem -= NELEC - 1 - i; ++i; }
        const int j = i + 1 + rem;
        const float dx = xyz[3*i+0] - xyz[3*j+0];
        const float dy = xyz[3*i+1] - xyz[3*j+1];
        const float dz = xyz[3*i+2] - xyz[3*j+2];
        const float dd = sqrtf(dx*dx + dy*dy + dz*dz);
        rbf_filter(dd, wfS, bfS, uoff_ee, filt + ee_p*FPAD);
    }
    __syncthreads();

    // ---------------- ee interaction layers (1 barrier each) ----------------
    ee_layer(h0, h1, filt, wr, wl_ee + 0*FEAT*FEAT, bl_ee + 0*FEAT, w, lane);
    __syncthreads();
    ee_layer(h1, h0, filt, wr, wl_ee + 1*FEAT*FEAT, bl_ee + 1*FEAT, w, lane);
    __syncthreads();

    // ---------------- S5a: stage wf_en/bf_en || ee readout (w15, h0) --------
    {
        const float4* src = reinterpret_cast<const float4*>(wf_en);
        float4* dst = reinterpret_cast<float4*>(wfS);
        dst[tid] = src[tid];
        if (tid < FEAT) bfS[tid] = bf_en[tid];
    }
    if (w == 15) {   // kee = (sum_n h0[n]) . wr + br  (f64 tail)
        float s = 0.f;
        #pragma unroll
        for (int n = 0; n < NELEC; ++n) s += h0[n*FEAT + lane];
        double dv = (double)s * (double)wr_ee[lane];
        #pragma unroll
        for (int o = 32; o > 0; o >>= 1) dv += __shfl_xor(dv, o, 64);
        if (lane == 0) *keeP = dv + (double)br_ee[0];
    }
    __syncthreads();

    // ---------------- S5b: en filter + en h1-init ----------------
    if (en_ok) {
        const int a = en_p / NELEC;
        const int e = en_p - a*NELEC;
        const float dx = xyz[3*e+0] - axyz[3*a+0];
        const float dy = xyz[3*e+1] - axyz[3*a+1];
        const float dz = xyz[3*e+2] - axyz[3*a+2];
        const float dd = sqrtf(dx*dx + dy*dy + dz*dz);
        rbf_filter(dd, wfS, bfS, uoff_en, filt + en_p*FPAD);
    }
    if (hr >= 0) {
        #pragma unroll
        for (int r = 0; r < 8; ++r) {
            const int idx = hr*64 + lane + r*320;
            h1[idx] = emb_en[en_ty[idx >> 6]*FEAT + (idx & 63)];
        }
    }
    __syncthreads();

    // ---------------- en interaction layers ----------------
    en_layer(h1, h0, filt, wr, wl_en + 0*FEAT*FEAT, bl_en + 0*FEAT, w, lane);
    __syncthreads();
    en_layer(h0, h1, filt, wr, wl_en + 1*FEAT*FEAT, bl_en + 1*FEAT, w, lane);
    __syncthreads();

    // ---------------- final readout + combine ----------------
    if (w == 0) {
        float s = 0.f;
        #pragma unroll
        for (int n = 0; n < NNEN; ++n) s += h1[n*FEAT + lane];
        double dv = (double)s * (double)wr_en[lane];
        #pragma unroll
        for (int o = 32; o > 0; o >>= 1) dv += __shfl_xor(dv, o, 64);
        if (lane == 0) out[b] = (float)exp(dv + (double)br_en[0] + *keeP);
    }
}

// ==========================================================================
extern "C" void kernel_launch(void* const* d_in, const int* in_sizes, int n_in,
                              void* d_out, int out_size, void* d_ws, size_t ws_size,
                              hipStream_t stream) {
    const float* pos    = (const float*)d_in[0];
    const float* atoms  = (const float*)d_in[1];
    const float* emb_ee = (const float*)d_in[2];
    const float* wf_ee  = (const float*)d_in[3];
    const float* bf_ee  = (const float*)d_in[4];
    const float* wl_ee  = (const float*)d_in[5];
    const float* bl_ee  = (const float*)d_in[6];
    const float* wr_ee  = (const float*)d_in[7];
    const float* br_ee  = (const float*)d_in[8];
    const float* emb_en = (const float*)d_in[9];
    const float* wf_en  = (const float*)d_in[10];
    const float* bf_en  = (const float*)d_in[11];
    const float* wl_en  = (const float*)d_in[12];
    const float* bl_en  = (const float*)d_in[13];
    const float* wr_en  = (const float*)d_in[14];
    const float* br_en  = (const float*)d_in[15];
    const int*   ee_ty  = (const int*)d_in[18];
    const int*   en_ty  = (const int*)d_in[21];

    float* out = (float*)d_out;        // [512]

    (void)hipFuncSetAttribute((const void*)fused_kernel,
            hipFuncAttributeMaxDynamicSharedMemorySize, SM_TOTAL*(int)sizeof(float));

    fused_kernel<<<NB, BLOCK, SM_TOTAL*sizeof(float), stream>>>(
        pos, atoms,
        emb_ee, wf_ee, bf_ee, wl_ee, bl_ee, wr_ee, br_ee,
        emb_en, wf_en, bf_en, wl_en, bl_en, wr_en, br_en,
        ee_ty, en_ty, out);
}

// Round 7
// 211.086 us; speedup vs baseline: 3.1043x; 1.2551x over previous
//
#include <hip/hip_runtime.h>
#include <math.h>

#define NB      512
#define NELEC   30
#define NATOMS  10
#define NNEN    40      // en graph nodes: 30 electrons + 10 atoms
#define FEAT    64
#define KRBF    64
#define BLOCK   1024
#define NWAVES  (BLOCK/64)
#define NPEE    435     // unique elec-elec pairs
#define NPEN    300     // unique elec-nuc pairs
#define TILE    32      // feature tile per filter thread (pair-half)
#define FPAD    65      // filt row stride (+1): lanes hit banks (p+f)%32, 2-way = free

// ---------------- LDS layout (floats) ----------------
// kee(double)@0 | h0[40][64] | h1[40][64] | filt[435][65] | wrS[16][64]
#define OFF_KEE   0                         // byte 0, 8B-aligned
#define H0_OFF    4
#define H1_OFF    (H0_OFF + NNEN*FEAT)      // 2564
#define FILT_OFF  (H1_OFF + NNEN*FEAT)      // 5124
#define WR_OFF    (FILT_OFF + NPEE*FPAD)    // 33399 -> pad to 33400 (16B align)
#define WR_ALN    33400
#define SM_TOTAL  (WR_ALN + NWAVES*64)      // 34424 fl = 137696 B -> 1 block/CU

// triangular pair index base for row i (i<j pairs of 30 electrons)
__device__ __forceinline__ int ee_base(int i) { return 29*i - ((i*(i-1))>>1); }

// ==========================================================================
// RBF filter: facc = tanh(bf + sum_k exp(-(dd-ck)^2) * wf[k]) for one
// 32-feature half. uoff is a readfirstlane SGPR so bf/wf rows are provably
// wave-uniform -> s_load (scalar pipe; R6 proved the LDS ds_read path costs
// 16x the issue slots). unroll 4 doubles R4's s_load prefetch depth — the
// k-loop was stalling on scalar-load latency every 2 steps (R7 test lever).
// FP value sequence identical to R3/R4 passing kernels.
// ==========================================================================
__device__ __forceinline__ void rbf_filter(float dd, const float* __restrict__ wf,
                                           const float* __restrict__ bf,
                                           int uoff, float* __restrict__ dstrow)
{
    float facc[TILE];
    const float* bfH = bf + uoff;                    // uniform -> s_load
    #pragma unroll
    for (int f = 0; f < TILE; ++f) facc[f] = bfH[f];
    #pragma unroll 4
    for (int k = 0; k < KRBF; ++k) {
        const float ck = (float)((double)k * (8.0/63.0));
        const float t  = dd - ck;
        const float rk = expf(-t*t);
        const float* wrow = wf + k*FEAT + uoff;      // uniform row -> s_load
        #pragma unroll
        for (int f = 0; f < TILE; ++f) facc[f] = fmaf(rk, wrow[f], facc[f]);
    }
    #pragma unroll
    for (int ff = 0; ff < TILE; ++ff) dstrow[uoff + ff] = tanhf(facc[ff]);
}

// ==========================================================================
// Fused per-wave ee layer: wave = node, lane = feature.
// iu = readfirstlane(i) -> pair-index/row-base arithmetic on SALU.
// Message sum -> private LDS row roundtrip (same-wave, lgkmcnt only) ->
// float4-broadcast dense -> hn. One barrier per layer (caller).
// ==========================================================================
__device__ __forceinline__ void ee_layer(const float* __restrict__ hc,
                                         float* __restrict__ hn,
                                         const float* __restrict__ filt,
                                         float* __restrict__ wr,
                                         const float* __restrict__ wlL,
                                         const float* __restrict__ blL,
                                         int w, int lane)
{
    for (int i = w; i < NELEC; i += NWAVES) {
        const int iu = __builtin_amdgcn_readfirstlane(i);   // SALU addressing
        float a = 0.f;
        #pragma unroll
        for (int j = 0; j < NELEC; ++j) {
            if (j != iu) {
                int pp = (j < iu) ? (ee_base(j) + (iu - j - 1))
                                  : (ee_base(iu) + (j - iu - 1));
                a = fmaf(hc[j*FEAT + lane], filt[pp*FPAD + lane], a);
            }
        }
        wr[lane] = a;                         // same-wave roundtrip
        float a2 = 0.f;
        const float4* arow = reinterpret_cast<const float4*>(wr);
        #pragma unroll
        for (int k = 0; k < FEAT/4; ++k) {
            float4 av = arow[k];              // uniform -> LDS broadcast b128
            a2 = fmaf(av.x, wlL[(4*k+0)*FEAT + lane], a2);
            a2 = fmaf(av.y, wlL[(4*k+1)*FEAT + lane], a2);
            a2 = fmaf(av.z, wlL[(4*k+2)*FEAT + lane], a2);
            a2 = fmaf(av.w, wlL[(4*k+3)*FEAT + lane], a2);
        }
        hn[iu*FEAT + lane] = hc[iu*FEAT + lane] + tanhf(a2 + blL[lane]);
    }
}

__device__ __forceinline__ void en_layer(const float* __restrict__ hc,
                                         float* __restrict__ hn,
                                         const float* __restrict__ filt,
                                         float* __restrict__ wr,
                                         const float* __restrict__ wlL,
                                         const float* __restrict__ blL,
                                         int w, int lane)
{
    for (int n = w; n < NNEN; n += NWAVES) {
        const int nu = __builtin_amdgcn_readfirstlane(n);
        float a = 0.f;
        if (nu < NELEC) {            // scalar branch: electron node, atoms asc
            #pragma unroll
            for (int at = 0; at < NATOMS; ++at)
                a = fmaf(hc[(NELEC+at)*FEAT + lane],
                         filt[(at*NELEC + nu)*FPAD + lane], a);
        } else {                     // atom node: electrons ascending
            const int at = nu - NELEC;
            #pragma unroll
            for (int e2 = 0; e2 < NELEC; ++e2)
                a = fmaf(hc[e2*FEAT + lane],
                         filt[(at*NELEC + e2)*FPAD + lane], a);
        }
        wr[lane] = a;
        float a2 = 0.f;
        const float4* arow = reinterpret_cast<const float4*>(wr);
        #pragma unroll
        for (int k = 0; k < FEAT/4; ++k) {
            float4 av = arow[k];
            a2 = fmaf(av.x, wlL[(4*k+0)*FEAT + lane], a2);
            a2 = fmaf(av.y, wlL[(4*k+1)*FEAT + lane], a2);
            a2 = fmaf(av.z, wlL[(4*k+2)*FEAT + lane], a2);
            a2 = fmaf(av.w, wlL[(4*k+3)*FEAT + lane], a2);
        }
        hn[nu*FEAT + lane] = hc[nu*FEAT + lane] + tanhf(a2 + blL[lane]);
    }
}

// ==========================================================================
// Fused ee+en GNN. One block per batch. out[b] = exp(k_ee + k_en).
// No register state crosses any barrier (R5 lesson). Filters read pos/atoms
// straight from global (96/30 floats, L1-resident — same bits as the old
// LDS staging) so the ee filter starts at cycle 0.
// Segments (6 barriers):
//  S0 [w0-13: ee-filter] || [w14-15: ee h0-init]           | barrier
//  L1 ee-l0 h0->h1 | L2 ee-l1 h1->h0                       | barrier each
//  S3 [w15: ee-readout(h0)] || [en-filter waves] || [hr: en h1-init] | barrier
//  L4 en-l0 h1->h0 | L5 en-l1 h0->h1                       | barrier each
//  S6 w0: final readout(h1) + combine
// ==========================================================================
__global__ __launch_bounds__(BLOCK)
void fused_kernel(const float* __restrict__ pos,
                  const float* __restrict__ atoms,
                  const float* __restrict__ emb_ee,
                  const float* __restrict__ wf_ee,
                  const float* __restrict__ bf_ee,
                  const float* __restrict__ wl_ee,
                  const float* __restrict__ bl_ee,
                  const float* __restrict__ wr_ee,
                  const float* __restrict__ br_ee,
                  const float* __restrict__ emb_en,
                  const float* __restrict__ wf_en,
                  const float* __restrict__ bf_en,
                  const float* __restrict__ wl_en,
                  const float* __restrict__ bl_en,
                  const float* __restrict__ wr_en,
                  const float* __restrict__ br_en,
                  const int*   __restrict__ ee_ty,
                  const int*   __restrict__ en_ty,
                  float*       __restrict__ out)
{
    extern __shared__ float sm[];
    double* keeP = reinterpret_cast<double*>(sm + OFF_KEE);
    float*  h0   = sm + H0_OFF;      // [40][64]
    float*  h1   = sm + H1_OFF;      // [40][64]
    float*  filt = sm + FILT_OFF;    // [435][65]
    float*  wrS  = sm + WR_ALN;      // [16][64]

    const int tid  = threadIdx.x;
    const int b    = blockIdx.x;
    const int lane = tid & 63;
    const int w    = tid >> 6;
    float* wr = wrS + w*64;          // this wave's private agg row

    const float* posB = pos + b*NELEC*3;

    // ---- wave roles ----
    // ee filter: waves 0-13 (t = w>=7), pair = (w mod 7)*64+lane -> SIMD (4,4,3,3)
    const int  ee_t   = (w >= 7) ? 1 : 0;
    const int  ee_p   = ((w >= 7 ? w - 7 : w) << 6) | lane;
    const bool ee_ok  = (w < 14) && (ee_p < NPEE);
    // en filter: active waves {0,1,2,3,4, 9,10,11,13,14} -> SIMD (2,3,3,2)
    const int  v      = w & 7;
    const int  en_blk = (w < 8) ? (v < 5 ? v : -1)
                                : ((v >= 1 && v <= 3) ? v - 1
                                   : (v == 5 || v == 6) ? v - 2 : -1);
    const int  en_t   = (w >= 8) ? 1 : 0;
    const int  en_p   = (en_blk < 0) ? 0 : ((en_blk << 6) | lane);
    const bool en_ok  = (en_blk >= 0) && (en_p < NPEN);
    // en h-init: waves {5,6,7,8,12} (disjoint from en-filter waves and w15)
    const int  hr     = (w == 5) ? 0 : (w == 6) ? 1 : (w == 7) ? 2
                      : (w == 8) ? 3 : (w == 12) ? 4 : -1;

    const int uoff_ee = __builtin_amdgcn_readfirstlane(ee_t * TILE);
    const int uoff_en = __builtin_amdgcn_readfirstlane(en_t * TILE);

    // ---------------- S0: ee filter (w0-13) || ee h0-init (w14-15) --------
    if (ee_ok) {
        int i = 0, rem = ee_p;
        while (rem >= NELEC - 1 - i) { rem -= NELEC - 1 - i; ++i; }
        const int j = i + 1 + rem;
        const float dx = posB[3*i+0] - posB[3*j+0];
        const float dy = posB[3*i+1] - posB[3*j+1];
        const float dz = posB[3*i+2] - posB[3*j+2];
        const float dd = sqrtf(dx*dx + dy*dy + dz*dz);
        rbf_filter(dd, wf_ee, bf_ee, uoff_ee, filt + ee_p*FPAD);
    }
    if (w >= 14) {   // 128 threads init h0 (1920 items, 15 iters)
        for (int idx = tid - 14*64; idx < NELEC*FEAT; idx += 128) {
            int n = idx >> 6, f = idx & 63;
            h0[idx] = emb_ee[ee_ty[n]*FEAT + f];
        }
    }
    __syncthreads();

    // ---------------- ee interaction layers (1 barrier each) --------------
    ee_layer(h0, h1, filt, wr, wl_ee + 0*FEAT*FEAT, bl_ee + 0*FEAT, w, lane);
    __syncthreads();
    ee_layer(h1, h0, filt, wr, wl_ee + 1*FEAT*FEAT, bl_ee + 1*FEAT, w, lane);
    __syncthreads();

    // ------- S3: ee readout (w15, h0) || en filter || en h1-init ----------
    if (en_ok) {
        const int a = en_p / NELEC;
        const int e = en_p - a*NELEC;
        const float dx = posB[3*e+0] - atoms[3*a+0];
        const float dy = posB[3*e+1] - atoms[3*a+1];
        const float dz = posB[3*e+2] - atoms[3*a+2];
        const float dd = sqrtf(dx*dx + dy*dy + dz*dz);
        rbf_filter(dd, wf_en, bf_en, uoff_en, filt + en_p*FPAD);
    }
    if (hr >= 0) {   // en h -> h1 (2560 items on 5 waves, 8 iters)
        #pragma unroll
        for (int r = 0; r < 8; ++r) {
            const int idx = hr*64 + lane + r*320;
            h1[idx] = emb_en[en_ty[idx >> 6]*FEAT + (idx & 63)];
        }
    }
    if (w == 15) {   // kee = (sum_n h0[n]) . wr + br  (f64 tail)
        float s = 0.f;
        #pragma unroll
        for (int n = 0; n < NELEC; ++n) s += h0[n*FEAT + lane];
        double dv = (double)s * (double)wr_ee[lane];
        #pragma unroll
        for (int o = 32; o > 0; o >>= 1) dv += __shfl_xor(dv, o, 64);
        if (lane == 0) *keeP = dv + (double)br_ee[0];
    }
    __syncthreads();

    // ---------------- en interaction layers -------------------------------
    en_layer(h1, h0, filt, wr, wl_en + 0*FEAT*FEAT, bl_en + 0*FEAT, w, lane);
    __syncthreads();
    en_layer(h0, h1, filt, wr, wl_en + 1*FEAT*FEAT, bl_en + 1*FEAT, w, lane);
    __syncthreads();

    // ---------------- final readout + combine -----------------------------
    if (w == 0) {
        float s = 0.f;
        #pragma unroll
        for (int n = 0; n < NNEN; ++n) s += h1[n*FEAT + lane];
        double dv = (double)s * (double)wr_en[lane];
        #pragma unroll
        for (int o = 32; o > 0; o >>= 1) dv += __shfl_xor(dv, o, 64);
        if (lane == 0) out[b] = (float)exp(dv + (double)br_en[0] + *keeP);
    }
}

// ==========================================================================
extern "C" void kernel_launch(void* const* d_in, const int* in_sizes, int n_in,
                              void* d_out, int out_size, void* d_ws, size_t ws_size,
                              hipStream_t stream) {
    const float* pos    = (const float*)d_in[0];
    const float* atoms  = (const float*)d_in[1];
    const float* emb_ee = (const float*)d_in[2];
    const float* wf_ee  = (const float*)d_in[3];
    const float* bf_ee  = (const float*)d_in[4];
    const float* wl_ee  = (const float*)d_in[5];
    const float* bl_ee  = (const float*)d_in[6];
    const float* wr_ee  = (const float*)d_in[7];
    const float* br_ee  = (const float*)d_in[8];
    const float* emb_en = (const float*)d_in[9];
    const float* wf_en  = (const float*)d_in[10];
    const float* bf_en  = (const float*)d_in[11];
    const float* wl_en  = (const float*)d_in[12];
    const float* bl_en  = (const float*)d_in[13];
    const float* wr_en  = (const float*)d_in[14];
    const float* br_en  = (const float*)d_in[15];
    const int*   ee_ty  = (const int*)d_in[18];
    const int*   en_ty  = (const int*)d_in[21];

    float* out = (float*)d_out;        // [512]

    (void)hipFuncSetAttribute((const void*)fused_kernel,
            hipFuncAttributeMaxDynamicSharedMemorySize, SM_TOTAL*(int)sizeof(float));

    fused_kernel<<<NB, BLOCK, SM_TOTAL*sizeof(float), stream>>>(
        pos, atoms,
        emb_ee, wf_ee, bf_ee, wl_ee, bl_ee, wr_ee, br_ee,
        emb_en, wf_en, bf_en, wl_en, bl_en, wr_en, br_en,
        ee_ty, en_ty, out);
}